// Round 1
// baseline (2248.655 us; speedup 1.0000x reference)
//
#include <hip/hip_runtime.h>
#include <hip/hip_bf16.h>
#include <cstdint>
#include <cstddef>

typedef __bf16 bf16_t;
typedef __bf16 bf16x8 __attribute__((ext_vector_type(8)));
typedef __bf16 bf16x4 __attribute__((ext_vector_type(4)));
typedef float  f32x4  __attribute__((ext_vector_type(4)));

#define MFMA_B16(A, Bv, Cv) __builtin_amdgcn_mfma_f32_16x16x32_bf16((A), (Bv), (Cv), 0, 0, 0)

__device__ __forceinline__ float blo(unsigned u) { return __uint_as_float(u << 16); }
__device__ __forceinline__ float bhi(unsigned u) { return __uint_as_float(u & 0xffff0000u); }

__device__ __forceinline__ void unpack8(uint4 u, float* f) {
  f[0] = blo(u.x); f[1] = bhi(u.x);
  f[2] = blo(u.y); f[3] = bhi(u.y);
  f[4] = blo(u.z); f[5] = bhi(u.z);
  f[6] = blo(u.w); f[7] = bhi(u.w);
}

// ---------------------------------------------------------------------------
// Stage A: qh/kh/vh projections.  C[p,o] = sum_c X[c,p] * W[o,c], bf16 MFMA.
// Output layout: [b][n][p][d] bf16 (d contiguous per pixel).
// grid: [3 proj][4 b][4 otile(128)][128 ptile(128)] = 6144 blocks x 256 thr
// ---------------------------------------------------------------------------
__global__ __launch_bounds__(256) void proj_kernel(
    const float* __restrict__ xq, const float* __restrict__ xk, const float* __restrict__ xv,
    const float* __restrict__ Wq, const float* __restrict__ Wk, const float* __restrict__ Wv,
    bf16_t* __restrict__ qh, bf16_t* __restrict__ kh, bf16_t* __restrict__ vh)
{
  int bid = blockIdx.x;
  const int pt = bid & 127; bid >>= 7;
  const int ot = bid & 3;   bid >>= 2;
  const int b  = bid & 3;   bid >>= 2;
  const int proj = bid;

  const float* X = (proj == 0) ? xq : (proj == 1) ? xk : xv;
  const float* W = (proj == 0) ? Wq : (proj == 1) ? Wk : Wv;
  bf16_t* OUT    = (proj == 0) ? qh : (proj == 1) ? kh : vh;

  const int p0 = pt * 128, o0 = ot * 128;
  __shared__ __align__(16) bf16_t Xl[128 * 64];  // [p][k], 16B-chunk XOR swizzle
  __shared__ __align__(16) bf16_t Wl[128 * 64];  // [o][k], 16B-chunk XOR swizzle

  const int tid = threadIdx.x;
  const int lane = tid & 63, wv = tid >> 6;
  const int wp = (wv & 1) * 64, wo = (wv >> 1) * 64;
  const int l15 = lane & 15, q4 = lane >> 4;

  f32x4 acc[4][4];
#pragma unroll
  for (int i = 0; i < 4; ++i)
#pragma unroll
    for (int j = 0; j < 4; ++j) acc[i][j] = (f32x4){0.f, 0.f, 0.f, 0.f};

  const size_t xbase = (size_t)b * 256 * 16384;

  for (int kc = 0; kc < 4; ++kc) {
    const int c0 = kc * 64;
    __syncthreads();
    // stage X tile: global [c][p] fp32 -> LDS [p][k] bf16 (transpose)
#pragma unroll
    for (int t = 0; t < 8; ++t) {
      int task = t * 256 + tid;           // 2048 tasks: (c 64) x (p4 32)
      int c = task >> 5, p4 = task & 31;
      float4 v4 = *(const float4*)(X + xbase + (size_t)(c0 + c) * 16384 + p0 + p4 * 4);
      const float* vf = &v4.x;
#pragma unroll
      for (int i = 0; i < 4; ++i) {
        int p = p4 * 4 + i;
        int gs = (c >> 3) ^ (p & 7);
        Xl[(p << 6) + (gs << 3) + (c & 7)] = (bf16_t)vf[i];
      }
    }
    // stage W tile: global [o][c] fp32 -> LDS [o][k] bf16
#pragma unroll
    for (int t = 0; t < 8; ++t) {
      int task = t * 256 + tid;           // 2048 tasks: (o 128) x (c4 16)
      int o = task >> 4, c4 = task & 15;
      float4 w4 = *(const float4*)(W + (size_t)(o0 + o) * 256 + c0 + c4 * 4);
      int kb = c4 * 4;
      int gs = (kb >> 3) ^ (o & 7);
      bf16x4 pk;
      pk[0] = (bf16_t)w4.x; pk[1] = (bf16_t)w4.y; pk[2] = (bf16_t)w4.z; pk[3] = (bf16_t)w4.w;
      *(bf16x4*)&Wl[(o << 6) + (gs << 3) + (kb & 7)] = pk;
    }
    __syncthreads();
#pragma unroll
    for (int ks = 0; ks < 2; ++ks) {
      const int gq = ks * 4 + q4;         // 16B chunk index within the 64-k row
      bf16x8 af[4], bfr[4];
#pragma unroll
      for (int i = 0; i < 4; ++i) {
        int p = wp + i * 16 + l15;        // A[m=lane&15][k=quad*8+j]
        af[i] = *(const bf16x8*)&Xl[(p << 6) + ((gq ^ (p & 7)) << 3)];
      }
#pragma unroll
      for (int j = 0; j < 4; ++j) {
        int o = wo + j * 16 + l15;        // B[k=quad*8+j][n=lane&15]
        bfr[j] = *(const bf16x8*)&Wl[(o << 6) + ((gq ^ (o & 7)) << 3)];
      }
#pragma unroll
      for (int i = 0; i < 4; ++i)
#pragma unroll
        for (int j = 0; j < 4; ++j)
          acc[i][j] = MFMA_B16(af[i], bfr[j], acc[i][j]);
    }
  }

  // epilogue: D row=p=(quad*4+r), col=o=(lane&15)  ->  [b][n][p][d]
#pragma unroll
  for (int i = 0; i < 4; ++i) {
#pragma unroll
    for (int j = 0; j < 4; ++j) {
      int o = o0 + wo + j * 16 + l15;
      int nn = o >> 6, d = o & 63;
#pragma unroll
      for (int r = 0; r < 4; ++r) {
        int p = p0 + wp + i * 16 + q4 * 4 + r;
        OUT[(((size_t)b * 8 + nn) * 16384 + p) * 64 + d] = (bf16_t)acc[i][j][r];
      }
    }
  }
}

// ---------------------------------------------------------------------------
// Stage B: 7x7 local attention per (b, head).  Block = 2 pixel rows x 128 w.
// Streaming 2-row LDS ring (zero-filled halo == reference zero padding, so
// out-of-bounds logits are exactly 0 and participate in the softmax).
// grid: [4 b][8 n][64 hchunk] = 2048 blocks x 256 thr
// ---------------------------------------------------------------------------
__global__ __launch_bounds__(256) void attn_kernel(
    const bf16_t* __restrict__ qh, const bf16_t* __restrict__ kh,
    const bf16_t* __restrict__ vh, bf16_t* __restrict__ ao)
{
  int bid = blockIdx.x;
  const int hc = bid & 63; bid >>= 6;
  const int n = bid & 7;   bid >>= 3;
  const int b = bid;

  const int tid = threadIdx.x;
  const int w = tid & 127, lr = tid >> 7;
  const int h = hc * 2 + lr;
  const int hbase = hc * 2;

  const size_t headoff = ((size_t)b * 8 + n) * 16384 * 64;
  const bf16_t* Qh = qh + headoff;
  const bf16_t* Kh = kh + headoff;
  const bf16_t* Vh = vh + headoff;

  __shared__ __align__(16) bf16_t ring[2][134 * 64];  // [slot][pix(-3..130)][d], swizzled
  __shared__ bf16_t attn_s[256][50];                  // per-thread 49 scores / weights

  uint4 qreg[8];
  {
    const uint4* qp = (const uint4*)(Qh + ((size_t)h * 128 + w) * 64);
#pragma unroll
    for (int c8 = 0; c8 < 8; ++c8) qreg[c8] = qp[c8];
  }

  auto load_row = [&](const bf16_t* SRC, int r, int slot) {
    const bool vr = (r >= 0) && (r < 128);
#pragma unroll
    for (int t = 0; t < 5; ++t) {
      int task = t * 256 + tid;            // 134*8 = 1072 16B-chunk tasks
      if (task < 1072) {
        int pix = task >> 3, g = task & 7;
        int ww = pix - 3;
        uint4 val = make_uint4(0u, 0u, 0u, 0u);
        if (vr && ww >= 0 && ww < 128)
          val = *(const uint4*)(SRC + ((size_t)r * 128 + ww) * 64 + g * 8);
        int gs = g ^ (pix & 7);
        *(uint4*)&ring[slot][(pix << 6) + (gs << 3)] = val;
      }
    }
  };

  // ---- pass 1: correlation scores ----
  load_row(Kh, hbase - 3, 0);
  load_row(Kh, hbase - 2, 1);
  __syncthreads();

  float mx = -1e30f;
#pragma unroll 1
  for (int dy = 0; dy < 7; ++dy) {
    const bf16_t* myrow = ring[(dy + lr) & 1];   // row = hbase + lr + dy - 3
    float dot[7];
#pragma unroll
    for (int dx = 0; dx < 7; ++dx) dot[dx] = 0.f;
#pragma unroll
    for (int c8 = 0; c8 < 8; ++c8) {
      float qf[8];
      unpack8(qreg[c8], qf);
#pragma unroll
      for (int dx = 0; dx < 7; ++dx) {
        int pix = w + dx;
        int gs = c8 ^ (pix & 7);
        uint4 kc = *(const uint4*)&myrow[(pix << 6) + (gs << 3)];
        float kf[8];
        unpack8(kc, kf);
        dot[dx] += qf[0]*kf[0] + qf[1]*kf[1] + qf[2]*kf[2] + qf[3]*kf[3]
                 + qf[4]*kf[4] + qf[5]*kf[5] + qf[6]*kf[6] + qf[7]*kf[7];
      }
    }
#pragma unroll
    for (int dx = 0; dx < 7; ++dx) {
      mx = fmaxf(mx, dot[dx]);
      attn_s[tid][dy * 7 + dx] = (bf16_t)dot[dx];
    }
    __syncthreads();
    if (dy < 6) {
      load_row(Kh, hbase + dy - 1, dy & 1);      // replaces dead row hbase+dy-3
      __syncthreads();
    }
  }

  // softmax over 49 (temperature 8); keep unnormalized exp, fold 1/sum at end
  float ssum = 0.f;
#pragma unroll
  for (int i = 0; i < 49; ++i) {
    float s = (float)attn_s[tid][i];
    float e = __expf((s - mx) * 0.125f);
    ssum += e;
    attn_s[tid][i] = (bf16_t)e;
  }
  const float oinv = 1.0f / ssum;

  // ---- pass 2: weighted V ----
  __syncthreads();
  load_row(Vh, hbase - 3, 0);
  load_row(Vh, hbase - 2, 1);
  __syncthreads();

  float outv[64];
#pragma unroll
  for (int d = 0; d < 64; ++d) outv[d] = 0.f;

#pragma unroll 1
  for (int dy = 0; dy < 7; ++dy) {
    const bf16_t* myrow = ring[(dy + lr) & 1];
    float a[7];
#pragma unroll
    for (int dx = 0; dx < 7; ++dx) a[dx] = (float)attn_s[tid][dy * 7 + dx];
#pragma unroll
    for (int c8 = 0; c8 < 8; ++c8) {
#pragma unroll
      for (int dx = 0; dx < 7; ++dx) {
        int pix = w + dx;
        int gs = c8 ^ (pix & 7);
        uint4 vc = *(const uint4*)&myrow[(pix << 6) + (gs << 3)];
        float vf[8];
        unpack8(vc, vf);
#pragma unroll
        for (int jj = 0; jj < 8; ++jj) outv[c8 * 8 + jj] += a[dx] * vf[jj];
      }
    }
    __syncthreads();
    if (dy < 6) {
      load_row(Vh, hbase + dy - 1, dy & 1);
      __syncthreads();
    }
  }

  // store, layout ao[b][p][o=n*64+d] bf16 (o contiguous per pixel for stage C)
  bf16_t* dst = ao + (((size_t)b * 16384) + (size_t)h * 128 + w) * 512 + n * 64;
#pragma unroll
  for (int c8 = 0; c8 < 8; ++c8) {
    bf16x8 ov;
#pragma unroll
    for (int jj = 0; jj < 8; ++jj) ov[jj] = (bf16_t)(outv[c8 * 8 + jj] * oinv);
    *(bf16x8*)(dst + c8 * 8) = ov;
  }
}

// ---------------------------------------------------------------------------
// Stage C: o = Wfc @ ao + residual, then LayerNorm over C=256, fused.
// C[c,p] orientation: residual loads + final stores coalesced in [b][c][p].
// grid: [4 b][256 ptile(64)] = 1024 blocks x 256 thr
// ---------------------------------------------------------------------------
__global__ __launch_bounds__(256) void fc_ln_kernel(
    const bf16_t* __restrict__ ao, const float* __restrict__ Wfc,
    const float* __restrict__ resid, const float* __restrict__ lnw,
    const float* __restrict__ lnb, float* __restrict__ outp)
{
  int bid = blockIdx.x;
  const int pt = bid & 255;
  const int b = bid >> 8;
  const int p0 = pt * 64;

  const int tid = threadIdx.x;
  const int lane = tid & 63, wv = tid >> 6;
  const int c0w = wv * 64;
  const int l15 = lane & 15, q4 = lane >> 4;

  __shared__ __align__(16) bf16_t Al[256 * 64];  // Wfc tile [c][k]
  __shared__ __align__(16) bf16_t Bl[64 * 64];   // ao tile [p][k]
  __shared__ float lnws[256], lnbs[256];
  __shared__ float red[2][4][64];

  lnws[tid] = lnw[tid];
  lnbs[tid] = lnb[tid];

  f32x4 acc[4][4];
#pragma unroll
  for (int i = 0; i < 4; ++i)
#pragma unroll
    for (int j = 0; j < 4; ++j) acc[i][j] = (f32x4){0.f, 0.f, 0.f, 0.f};

  for (int kc = 0; kc < 8; ++kc) {
    const int k0 = kc * 64;
    __syncthreads();
#pragma unroll
    for (int t = 0; t < 16; ++t) {
      int task = t * 256 + tid;            // 4096 tasks: (c 256) x (k4 16)
      int c = task >> 4, k4 = task & 15;
      float4 w4 = *(const float4*)(Wfc + (size_t)c * 512 + k0 + k4 * 4);
      int kb = k4 * 4;
      int gs = (kb >> 3) ^ (c & 7);
      bf16x4 pk;
      pk[0] = (bf16_t)w4.x; pk[1] = (bf16_t)w4.y; pk[2] = (bf16_t)w4.z; pk[3] = (bf16_t)w4.w;
      *(bf16x4*)&Al[(c << 6) + (gs << 3) + (kb & 7)] = pk;
    }
#pragma unroll
    for (int t = 0; t < 2; ++t) {
      int task = t * 256 + tid;            // 512 tasks: (p 64) x (g 8)
      int p = task >> 3, g = task & 7;
      uint4 v4 = *(const uint4*)(ao + ((size_t)b * 16384 + p0 + p) * 512 + k0 + g * 8);
      int gs = g ^ (p & 7);
      *(uint4*)&Bl[(p << 6) + (gs << 3)] = v4;
    }
    __syncthreads();
#pragma unroll
    for (int ks = 0; ks < 2; ++ks) {
      const int gq = ks * 4 + q4;
      bf16x8 af[4], bfr[4];
#pragma unroll
      for (int i = 0; i < 4; ++i) {
        int c = c0w + i * 16 + l15;
        af[i] = *(const bf16x8*)&Al[(c << 6) + ((gq ^ (c & 7)) << 3)];
      }
#pragma unroll
      for (int j = 0; j < 4; ++j) {
        int p = j * 16 + l15;
        bfr[j] = *(const bf16x8*)&Bl[(p << 6) + ((gq ^ (p & 7)) << 3)];
      }
#pragma unroll
      for (int i = 0; i < 4; ++i)
#pragma unroll
        for (int j = 0; j < 4; ++j)
          acc[i][j] = MFMA_B16(af[i], bfr[j], acc[i][j]);
    }
  }

  // residual add + per-pixel channel sums (D row=c, col=p)
  float s[4], s2[4];
#pragma unroll
  for (int j = 0; j < 4; ++j) { s[j] = 0.f; s2[j] = 0.f; }
#pragma unroll
  for (int i = 0; i < 4; ++i) {
#pragma unroll
    for (int r = 0; r < 4; ++r) {
      int c = c0w + i * 16 + q4 * 4 + r;
      const float* rp = resid + ((size_t)b * 256 + c) * 16384 + p0;
#pragma unroll
      for (int j = 0; j < 4; ++j) {
        float v = acc[i][j][r] + rp[j * 16 + l15];
        acc[i][j][r] = v;
        s[j] += v; s2[j] += v * v;
      }
    }
  }
#pragma unroll
  for (int j = 0; j < 4; ++j) {            // reduce across the 4 lane-quads
    s[j]  += __shfl_xor(s[j], 16);
    s[j]  += __shfl_xor(s[j], 32);
    s2[j] += __shfl_xor(s2[j], 16);
    s2[j] += __shfl_xor(s2[j], 32);
  }
  if (q4 == 0) {
#pragma unroll
    for (int j = 0; j < 4; ++j) {
      red[0][wv][j * 16 + l15] = s[j];
      red[1][wv][j * 16 + l15] = s2[j];
    }
  }
  __syncthreads();
#pragma unroll
  for (int j = 0; j < 4; ++j) {
    int pl = j * 16 + l15;
    float ts  = red[0][0][pl] + red[0][1][pl] + red[0][2][pl] + red[0][3][pl];
    float ts2 = red[1][0][pl] + red[1][1][pl] + red[1][2][pl] + red[1][3][pl];
    float mean = ts * (1.f / 256.f);
    float var  = ts2 * (1.f / 256.f) - mean * mean;
    float rstd = rsqrtf(var + 1e-6f);
#pragma unroll
    for (int i = 0; i < 4; ++i) {
#pragma unroll
      for (int r = 0; r < 4; ++r) {
        int c = c0w + i * 16 + q4 * 4 + r;
        outp[((size_t)b * 256 + c) * 16384 + p0 + pl] =
            (acc[i][j][r] - mean) * rstd * lnws[c] + lnbs[c];
      }
    }
  }
}

// ---------------------------------------------------------------------------
extern "C" void kernel_launch(void* const* d_in, const int* in_sizes, int n_in,
                              void* d_out, int out_size, void* d_ws, size_t ws_size,
                              hipStream_t stream) {
  const float* q   = (const float*)d_in[0];
  const float* k   = (const float*)d_in[1];
  const float* v   = (const float*)d_in[2];
  const float* Wq  = (const float*)d_in[3];
  const float* Wk  = (const float*)d_in[4];
  const float* Wv  = (const float*)d_in[5];
  const float* Wfc = (const float*)d_in[6];
  const float* lnw = (const float*)d_in[7];
  const float* lnb = (const float*)d_in[8];
  float* outp = (float*)d_out;

  // workspace: 4 x 33,554,432 bf16 = 268 MB, fully rewritten every call
  bf16_t* qh = (bf16_t*)d_ws;
  bf16_t* kh = qh + 33554432ULL;
  bf16_t* vh = kh + 33554432ULL;
  bf16_t* ao = vh + 33554432ULL;

  proj_kernel<<<dim3(6144), dim3(256), 0, stream>>>(q, k, v, Wq, Wk, Wv, qh, kh, vh);
  attn_kernel<<<dim3(2048), dim3(256), 0, stream>>>(qh, kh, vh, ao);
  fc_ln_kernel<<<dim3(1024), dim3(256), 0, stream>>>(ao, Wfc, q, lnw, lnb, outp);
}

// Round 2
// 792.474 us; speedup vs baseline: 2.8375x; 2.8375x over previous
//
#include <hip/hip_runtime.h>
#include <hip/hip_bf16.h>
#include <cstdint>
#include <cstddef>

typedef _Float16 f16_t;
typedef _Float16 h2    __attribute__((ext_vector_type(2)));
typedef _Float16 f16x8 __attribute__((ext_vector_type(8)));
typedef float    f32x4 __attribute__((ext_vector_type(4)));

#define MFMA_F16(A, Bv, Cv) __builtin_amdgcn_mfma_f32_16x16x32_f16((A), (Bv), (Cv), 0, 0, 0)

__device__ __forceinline__ float fdot2_(h2 a, h2 b, float c) {
#if __has_builtin(__builtin_amdgcn_fdot2)
  return __builtin_amdgcn_fdot2(a, b, c, false);
#else
  return c + (float)a[0] * (float)b[0] + (float)a[1] * (float)b[1];
#endif
}

// ---------------------------------------------------------------------------
// Stage A: qh/kh/vh projections.  C[p,o] = sum_c X[c,p] * W[o,c], f16 MFMA.
// Output layout: [b][n][p][d] f16.
// grid: [3 proj][4 b][4 otile(128)][128 ptile(128)] = 6144 blocks x 256 thr
// ---------------------------------------------------------------------------
__global__ __launch_bounds__(256) void proj_kernel(
    const float* __restrict__ xq, const float* __restrict__ xk, const float* __restrict__ xv,
    const float* __restrict__ Wq, const float* __restrict__ Wk, const float* __restrict__ Wv,
    f16_t* __restrict__ qh, f16_t* __restrict__ kh, f16_t* __restrict__ vh)
{
  int bid = blockIdx.x;
  const int pt = bid & 127; bid >>= 7;
  const int ot = bid & 3;   bid >>= 2;
  const int b  = bid & 3;   bid >>= 2;
  const int proj = bid;

  const float* X = (proj == 0) ? xq : (proj == 1) ? xk : xv;
  const float* W = (proj == 0) ? Wq : (proj == 1) ? Wk : Wv;
  f16_t* OUT     = (proj == 0) ? qh : (proj == 1) ? kh : vh;

  const int p0 = pt * 128, o0 = ot * 128;
  __shared__ __align__(16) f16_t Xl[128 * 64];  // [p][k], 16B-chunk XOR swizzle
  __shared__ __align__(16) f16_t Wl[128 * 64];  // [o][k], 16B-chunk XOR swizzle

  const int tid = threadIdx.x;
  const int lane = tid & 63, wv = tid >> 6;
  const int wp = (wv & 1) * 64, wo = (wv >> 1) * 64;
  const int l15 = lane & 15, q4 = lane >> 4;

  f32x4 acc[4][4];
#pragma unroll
  for (int i = 0; i < 4; ++i)
#pragma unroll
    for (int j = 0; j < 4; ++j) acc[i][j] = (f32x4){0.f, 0.f, 0.f, 0.f};

  const size_t xbase = (size_t)b * 256 * 16384;

  for (int kc = 0; kc < 4; ++kc) {
    const int c0 = kc * 64;
    __syncthreads();
#pragma unroll
    for (int t = 0; t < 8; ++t) {
      int task = t * 256 + tid;           // 2048 tasks: (c 64) x (p4 32)
      int c = task >> 5, p4 = task & 31;
      float4 v4 = *(const float4*)(X + xbase + (size_t)(c0 + c) * 16384 + p0 + p4 * 4);
      const float* vf = &v4.x;
#pragma unroll
      for (int i = 0; i < 4; ++i) {
        int p = p4 * 4 + i;
        int gs = (c >> 3) ^ (p & 7);
        Xl[(p << 6) + (gs << 3) + (c & 7)] = (f16_t)vf[i];
      }
    }
#pragma unroll
    for (int t = 0; t < 8; ++t) {
      int task = t * 256 + tid;           // 2048 tasks: (o 128) x (c4 16)
      int o = task >> 4, c4 = task & 15;
      float4 w4 = *(const float4*)(W + (size_t)(o0 + o) * 256 + c0 + c4 * 4);
      int kb = c4 * 4;
      int gs = (kb >> 3) ^ (o & 7);
      f16_t* dst = &Wl[(o << 6) + (gs << 3) + (kb & 7)];
      dst[0] = (f16_t)w4.x; dst[1] = (f16_t)w4.y; dst[2] = (f16_t)w4.z; dst[3] = (f16_t)w4.w;
    }
    __syncthreads();
#pragma unroll
    for (int ks = 0; ks < 2; ++ks) {
      const int gq = ks * 4 + q4;
      f16x8 af[4], bfr[4];
#pragma unroll
      for (int i = 0; i < 4; ++i) {
        int p = wp + i * 16 + l15;
        af[i] = *(const f16x8*)&Xl[(p << 6) + ((gq ^ (p & 7)) << 3)];
      }
#pragma unroll
      for (int j = 0; j < 4; ++j) {
        int o = wo + j * 16 + l15;
        bfr[j] = *(const f16x8*)&Wl[(o << 6) + ((gq ^ (o & 7)) << 3)];
      }
#pragma unroll
      for (int i = 0; i < 4; ++i)
#pragma unroll
        for (int j = 0; j < 4; ++j)
          acc[i][j] = MFMA_F16(af[i], bfr[j], acc[i][j]);
    }
  }

#pragma unroll
  for (int i = 0; i < 4; ++i) {
#pragma unroll
    for (int j = 0; j < 4; ++j) {
      int o = o0 + wo + j * 16 + l15;
      int nn = o >> 6, d = o & 63;
#pragma unroll
      for (int r = 0; r < 4; ++r) {
        int p = p0 + wp + i * 16 + q4 * 4 + r;
        OUT[(((size_t)b * 8 + nn) * 16384 + p) * 64 + d] = (f16_t)acc[i][j][r];
      }
    }
  }
}

// ---------------------------------------------------------------------------
// Stage B: 7x7 local attention, single pass, online softmax.
// Block = 2 pixel rows x 64 w.  thread = (lr, w, dg); dg = 32-channel half.
// 2-slot LDS ring of combined K|V rows (70 pix x 16 chunks x 16B, XOR swizzle).
// Zero-filled halo reproduces reference zero-padding (OOB logits = 0, included
// in softmax; OOB V contributes 0).
// grid: [4 b][8 n][64 rowpair][2 whalf] = 4096 blocks x 256 thr
// ---------------------------------------------------------------------------
__global__ __launch_bounds__(256, 4) void attn_kernel(
    const f16_t* __restrict__ qh, const f16_t* __restrict__ kh,
    const f16_t* __restrict__ vh, f16_t* __restrict__ ao)
{
  int bid = blockIdx.x;
  const int wh = bid & 1;  bid >>= 1;
  const int hh = bid & 63; bid >>= 6;
  const int n  = bid & 7;  bid >>= 3;
  const int b  = bid;
  const int h0 = hh * 2, w0 = wh * 64;

  const int tid = threadIdx.x;
  const int lr = tid >> 7;          // pixel row within block (wave-uniform)
  const int w  = (tid >> 1) & 63;   // pixel col within half-row
  const int dg = tid & 1;           // 32-channel group
  const int hp = h0 + lr;
  const int dg4 = dg * 4;

  const size_t headoff = ((size_t)b * 8 + n) * 16384 * 64;
  const f16_t* Qh = qh + headoff;
  const f16_t* Kh = kh + headoff;
  const f16_t* Vh = vh + headoff;

  __shared__ uint4 ring[2][70 * 16];  // [slot][pix*16 + (oc ^ (pix&15))]

  union Pack { uint4 u[4]; h2 h[16]; };

  // q fragment: 32 channels, packed f16 pairs
  Pack qu;
  {
    const uint4* qp = (const uint4*)(Qh + ((size_t)hp * 128 + w0 + w) * 64 + dg * 32);
    qu.u[0] = qp[0]; qu.u[1] = qp[1]; qu.u[2] = qp[2]; qu.u[3] = qp[3];
  }

  auto load_row = [&](int r, int slot) {
#pragma unroll
    for (int t = 0; t < 5; ++t) {
      int task = t * 256 + tid;            // 70*16 = 1120 16B-chunk tasks
      if (task < 1120) {
        int pix = task >> 4, oc = task & 15;
        int ww = w0 + pix - 3;
        uint4 val = make_uint4(0u, 0u, 0u, 0u);
        if (r >= 0 && r < 128 && ww >= 0 && ww < 128) {
          const f16_t* src = (oc < 8)
              ? (Kh + ((size_t)r * 128 + ww) * 64 + oc * 8)
              : (Vh + ((size_t)r * 128 + ww) * 64 + (oc - 8) * 8);
          val = *(const uint4*)src;
        }
        ring[slot][(pix << 4) + (oc ^ (pix & 15))] = val;
      }
    }
  };

  const float cscale = 0.18033688011112042f;  // (1/8) * log2(e)

  float m = -3.0e38f, l = 0.f;
  h2 outv[16];
#pragma unroll
  for (int j = 0; j < 16; ++j) outv[j] = (h2){(f16_t)0.f, (f16_t)0.f};

  load_row(h0 - 3, 0);
  __syncthreads();

#pragma unroll 1
  for (int it = 0; it < 8; ++it) {
    if (it < 7) load_row(h0 - 2 + it, (it + 1) & 1);  // prefetch next row
    const uint4* cur = ring[it & 1];
    const int dyi = it - lr;                           // wave-uniform
    if (dyi >= 0 && dyi < 7) {
      // ---- scores for this k-row ----
      float s[7];
#pragma unroll
      for (int dx = 0; dx < 7; ++dx) {
        const int pix = w + dx, sw = pix & 15, base = pix << 4;
        Pack ku;
        ku.u[0] = cur[base + ((dg4 + 0) ^ sw)];
        ku.u[1] = cur[base + ((dg4 + 1) ^ sw)];
        ku.u[2] = cur[base + ((dg4 + 2) ^ sw)];
        ku.u[3] = cur[base + ((dg4 + 3) ^ sw)];
        float acc = 0.f;
#pragma unroll
        for (int j = 0; j < 16; ++j) acc = fdot2_(qu.h[j], ku.h[j], acc);
        s[dx] = acc;
      }
#pragma unroll
      for (int dx = 0; dx < 7; ++dx)
        s[dx] = (s[dx] + __shfl_xor(s[dx], 1)) * cscale;  // full 64-ch dot, log2-scaled

      // ---- online softmax update ----
      float nm = m;
#pragma unroll
      for (int dx = 0; dx < 7; ++dx) nm = fmaxf(nm, s[dx]);
      float alpha = exp2f(m - nm);
      m = nm;
      l *= alpha;
      {
        f16_t ah = (f16_t)alpha;
        h2 a2 = (h2){ah, ah};
#pragma unroll
        for (int j = 0; j < 16; ++j) outv[j] *= a2;
      }
      h2 e2[7];
#pragma unroll
      for (int dx = 0; dx < 7; ++dx) {
        float e = exp2f(s[dx] - m);
        l += e;
        f16_t eh = (f16_t)e;
        e2[dx] = (h2){eh, eh};
      }
      // ---- weighted V ----
#pragma unroll
      for (int dx = 0; dx < 7; ++dx) {
        const int pix = w + dx, sw = pix & 15, base = pix << 4;
        Pack vu;
        vu.u[0] = cur[base + ((8 + dg4 + 0) ^ sw)];
        vu.u[1] = cur[base + ((8 + dg4 + 1) ^ sw)];
        vu.u[2] = cur[base + ((8 + dg4 + 2) ^ sw)];
        vu.u[3] = cur[base + ((8 + dg4 + 3) ^ sw)];
#pragma unroll
        for (int j = 0; j < 16; ++j) outv[j] = e2[dx] * vu.h[j] + outv[j];
      }
    }
    __syncthreads();
  }

  // epilogue: normalize, store 32 f16 channels
  float inv = 1.0f / l;
  f16_t ih = (f16_t)inv;
  h2 i2 = (h2){ih, ih};
  Pack ou;
#pragma unroll
  for (int j = 0; j < 16; ++j) ou.h[j] = outv[j] * i2;

  f16_t* dst = ao + (((size_t)b * 16384) + (size_t)hp * 128 + (w0 + w)) * 512 + n * 64 + dg * 32;
  uint4* d4 = (uint4*)dst;
  d4[0] = ou.u[0]; d4[1] = ou.u[1]; d4[2] = ou.u[2]; d4[3] = ou.u[3];
}

// ---------------------------------------------------------------------------
// Stage C: o = Wfc @ ao + residual, then LayerNorm over C=256, fused. f16 MFMA.
// grid: [4 b][256 ptile(64)] = 1024 blocks x 256 thr
// ---------------------------------------------------------------------------
__global__ __launch_bounds__(256) void fc_ln_kernel(
    const f16_t* __restrict__ ao, const float* __restrict__ Wfc,
    const float* __restrict__ resid, const float* __restrict__ lnw,
    const float* __restrict__ lnb, float* __restrict__ outp)
{
  int bid = blockIdx.x;
  const int pt = bid & 255;
  const int b = bid >> 8;
  const int p0 = pt * 64;

  const int tid = threadIdx.x;
  const int lane = tid & 63, wv = tid >> 6;
  const int c0w = wv * 64;
  const int l15 = lane & 15, q4 = lane >> 4;

  __shared__ __align__(16) f16_t Al[256 * 64];  // Wfc tile [c][k]
  __shared__ __align__(16) f16_t Bl[64 * 64];   // ao tile [p][k]
  __shared__ float lnws[256], lnbs[256];
  __shared__ float red[2][4][64];

  lnws[tid] = lnw[tid];
  lnbs[tid] = lnb[tid];

  f32x4 acc[4][4];
#pragma unroll
  for (int i = 0; i < 4; ++i)
#pragma unroll
    for (int j = 0; j < 4; ++j) acc[i][j] = (f32x4){0.f, 0.f, 0.f, 0.f};

  for (int kc = 0; kc < 8; ++kc) {
    const int k0 = kc * 64;
    __syncthreads();
#pragma unroll
    for (int t = 0; t < 16; ++t) {
      int task = t * 256 + tid;            // 4096 tasks: (c 256) x (k4 16)
      int c = task >> 4, k4 = task & 15;
      float4 w4 = *(const float4*)(Wfc + (size_t)c * 512 + k0 + k4 * 4);
      int kb = k4 * 4;
      int gs = (kb >> 3) ^ (c & 7);
      f16_t* dst = &Al[(c << 6) + (gs << 3) + (kb & 7)];
      dst[0] = (f16_t)w4.x; dst[1] = (f16_t)w4.y; dst[2] = (f16_t)w4.z; dst[3] = (f16_t)w4.w;
    }
#pragma unroll
    for (int t = 0; t < 2; ++t) {
      int task = t * 256 + tid;            // 512 tasks: (p 64) x (g 8)
      int p = task >> 3, g = task & 7;
      uint4 v4 = *(const uint4*)(ao + ((size_t)b * 16384 + p0 + p) * 512 + k0 + g * 8);
      int gs = g ^ (p & 7);
      *(uint4*)&Bl[(p << 6) + (gs << 3)] = v4;
    }
    __syncthreads();
#pragma unroll
    for (int ks = 0; ks < 2; ++ks) {
      const int gq = ks * 4 + q4;
      f16x8 af[4], bfr[4];
#pragma unroll
      for (int i = 0; i < 4; ++i) {
        int c = c0w + i * 16 + l15;
        af[i] = *(const f16x8*)&Al[(c << 6) + ((gq ^ (c & 7)) << 3)];
      }
#pragma unroll
      for (int j = 0; j < 4; ++j) {
        int p = j * 16 + l15;
        bfr[j] = *(const f16x8*)&Bl[(p << 6) + ((gq ^ (p & 7)) << 3)];
      }
#pragma unroll
      for (int i = 0; i < 4; ++i)
#pragma unroll
        for (int j = 0; j < 4; ++j)
          acc[i][j] = MFMA_F16(af[i], bfr[j], acc[i][j]);
    }
  }

  float s[4], s2[4];
#pragma unroll
  for (int j = 0; j < 4; ++j) { s[j] = 0.f; s2[j] = 0.f; }
#pragma unroll
  for (int i = 0; i < 4; ++i) {
#pragma unroll
    for (int r = 0; r < 4; ++r) {
      int c = c0w + i * 16 + q4 * 4 + r;
      const float* rp = resid + ((size_t)b * 256 + c) * 16384 + p0;
#pragma unroll
      for (int j = 0; j < 4; ++j) {
        float v = acc[i][j][r] + rp[j * 16 + l15];
        acc[i][j][r] = v;
        s[j] += v; s2[j] += v * v;
      }
    }
  }
#pragma unroll
  for (int j = 0; j < 4; ++j) {
    s[j]  += __shfl_xor(s[j], 16);
    s[j]  += __shfl_xor(s[j], 32);
    s2[j] += __shfl_xor(s2[j], 16);
    s2[j] += __shfl_xor(s2[j], 32);
  }
  if (q4 == 0) {
#pragma unroll
    for (int j = 0; j < 4; ++j) {
      red[0][wv][j * 16 + l15] = s[j];
      red[1][wv][j * 16 + l15] = s2[j];
    }
  }
  __syncthreads();
#pragma unroll
  for (int j = 0; j < 4; ++j) {
    int pl = j * 16 + l15;
    float ts  = red[0][0][pl] + red[0][1][pl] + red[0][2][pl] + red[0][3][pl];
    float ts2 = red[1][0][pl] + red[1][1][pl] + red[1][2][pl] + red[1][3][pl];
    float mean = ts * (1.f / 256.f);
    float var  = ts2 * (1.f / 256.f) - mean * mean;
    float rstd = rsqrtf(var + 1e-6f);
#pragma unroll
    for (int i = 0; i < 4; ++i) {
#pragma unroll
      for (int r = 0; r < 4; ++r) {
        int c = c0w + i * 16 + q4 * 4 + r;
        outp[((size_t)b * 256 + c) * 16384 + p0 + pl] =
            (acc[i][j][r] - mean) * rstd * lnws[c] + lnbs[c];
      }
    }
  }
}

// ---------------------------------------------------------------------------
extern "C" void kernel_launch(void* const* d_in, const int* in_sizes, int n_in,
                              void* d_out, int out_size, void* d_ws, size_t ws_size,
                              hipStream_t stream) {
  const float* q   = (const float*)d_in[0];
  const float* k   = (const float*)d_in[1];
  const float* v   = (const float*)d_in[2];
  const float* Wq  = (const float*)d_in[3];
  const float* Wk  = (const float*)d_in[4];
  const float* Wv  = (const float*)d_in[5];
  const float* Wfc = (const float*)d_in[6];
  const float* lnw = (const float*)d_in[7];
  const float* lnb = (const float*)d_in[8];
  float* outp = (float*)d_out;

  // workspace: 4 x 33,554,432 f16 = 268 MB, fully rewritten every call
  f16_t* qh = (f16_t*)d_ws;
  f16_t* kh = qh + 33554432ULL;
  f16_t* vh = kh + 33554432ULL;
  f16_t* ao = vh + 33554432ULL;

  proj_kernel<<<dim3(6144), dim3(256), 0, stream>>>(q, k, v, Wq, Wk, Wv, qh, kh, vh);
  attn_kernel<<<dim3(4096), dim3(256), 0, stream>>>(qh, kh, vh, ao);
  fc_ln_kernel<<<dim3(1024), dim3(256), 0, stream>>>(ao, Wfc, q, lnw, lnb, outp);
}

// Round 3
// 786.304 us; speedup vs baseline: 2.8598x; 1.0078x over previous
//
#include <hip/hip_runtime.h>
#include <hip/hip_bf16.h>
#include <cstdint>
#include <cstddef>

typedef _Float16 f16_t;
typedef _Float16 h2    __attribute__((ext_vector_type(2)));
typedef _Float16 f16x8 __attribute__((ext_vector_type(8)));
typedef float    f32x4 __attribute__((ext_vector_type(4)));

#define MFMA_F16(A, Bv, Cv) __builtin_amdgcn_mfma_f32_16x16x32_f16((A), (Bv), (Cv), 0, 0, 0)

__device__ __forceinline__ float fdot2_(h2 a, h2 b, float c) {
#if __has_builtin(__builtin_amdgcn_fdot2)
  return __builtin_amdgcn_fdot2(a, b, c, false);
#else
  return c + (float)a[0] * (float)b[0] + (float)a[1] * (float)b[1];
#endif
}

// ---------------------------------------------------------------------------
// W fp32 -> f16 converters (run while target ws region is dead).
// ---------------------------------------------------------------------------
__global__ __launch_bounds__(256) void wconvA_kernel(
    const float* __restrict__ Wq, const float* __restrict__ Wk,
    const float* __restrict__ Wv, f16_t* __restrict__ dst)
{
  int idx = blockIdx.x * 256 + threadIdx.x;        // 98304 float4 tasks
  int src = idx >> 15, off = idx & 32767;
  const float* W = (src == 0) ? Wq : (src == 1) ? Wk : Wv;
  float4 a = *(const float4*)(W + (size_t)off * 4);
  f16_t* d = dst + (size_t)src * 131072 + (size_t)off * 4;
  d[0] = (f16_t)a.x; d[1] = (f16_t)a.y; d[2] = (f16_t)a.z; d[3] = (f16_t)a.w;
}

__global__ __launch_bounds__(256) void wconvB_kernel(
    const float* __restrict__ Wfc, f16_t* __restrict__ dst)
{
  int idx = blockIdx.x * 256 + threadIdx.x;        // 32768 float4 tasks
  float4 a = *(const float4*)(Wfc + (size_t)idx * 4);
  f16_t* d = dst + (size_t)idx * 4;
  d[0] = (f16_t)a.x; d[1] = (f16_t)a.y; d[2] = (f16_t)a.z; d[3] = (f16_t)a.w;
}

// ---------------------------------------------------------------------------
// Stage A: projections.  Block = 128 pixels; X staged ONCE (64 KB LDS, f16,
// [p][k=256] with chunk swizzle g ^ (p&7) ^ ((p>>3)&7)); loop 4 otiles inside;
// B-fragments gathered directly from L2-hot W_f16 (no LDS, no barriers).
// grid: [3 proj][4 b][128 ptile] = 1536 blocks x 256 thr
// ---------------------------------------------------------------------------
__global__ __launch_bounds__(256, 2) void proj_kernel(
    const float* __restrict__ xq, const float* __restrict__ xk, const float* __restrict__ xv,
    const f16_t* __restrict__ Wall,
    f16_t* __restrict__ qh, f16_t* __restrict__ kh, f16_t* __restrict__ vh)
{
  int bid = blockIdx.x;
  const int pt = bid & 127; bid >>= 7;
  const int b  = bid & 3;   bid >>= 2;
  const int proj = bid;

  const float* X = (proj == 0) ? xq : (proj == 1) ? xk : xv;
  const f16_t* Wf = Wall + (size_t)proj * 131072;
  f16_t* OUT     = (proj == 0) ? qh : (proj == 1) ? kh : vh;

  const int p0 = pt * 128;
  __shared__ __align__(16) f16_t Xl[128 * 256];  // 64 KB

  const int tid = threadIdx.x;
  const int lane = tid & 63, wv = tid >> 6;
  const int wp = (wv & 1) * 64, wo = (wv >> 1) * 64;
  const int l15 = lane & 15, q4 = lane >> 4;

  const size_t xbase = (size_t)b * 256 * 16384;

  // stage X tile [c=256][p=128] fp32 -> LDS [p][k] f16, c-pairs as h2
#pragma unroll
  for (int t = 0; t < 16; ++t) {
    int task = t * 256 + tid;            // 4096 tasks: (c2 128) x (p4 32)
    int c2 = task >> 5, p4 = task & 31;
    int c0 = c2 * 2;
    float4 a0 = *(const float4*)(X + xbase + (size_t)c0 * 16384 + p0 + p4 * 4);
    float4 a1 = *(const float4*)(X + xbase + (size_t)(c0 + 1) * 16384 + p0 + p4 * 4);
    const float* f0 = &a0.x; const float* f1 = &a1.x;
    int g = c0 >> 3;
#pragma unroll
    for (int i = 0; i < 4; ++i) {
      int p = p4 * 4 + i;
      int sw = (p & 7) ^ ((p >> 3) & 7);
      h2 val = (h2){(f16_t)f0[i], (f16_t)f1[i]};
      *(h2*)&Xl[(p << 8) + ((g ^ sw) << 3) + (c0 & 7)] = val;
    }
  }
  __syncthreads();

#pragma unroll 1
  for (int ot = 0; ot < 4; ++ot) {
    f32x4 acc[4][4];
#pragma unroll
    for (int i = 0; i < 4; ++i)
#pragma unroll
      for (int j = 0; j < 4; ++j) acc[i][j] = (f32x4){0.f, 0.f, 0.f, 0.f};

#pragma unroll
    for (int kc = 0; kc < 4; ++kc) {
#pragma unroll
      for (int ks = 0; ks < 2; ++ks) {
        const int gq = kc * 8 + ks * 4 + q4;     // chunk 0..31
        f16x8 af[4], bfr[4];
#pragma unroll
        for (int i = 0; i < 4; ++i) {
          int p = wp + i * 16 + l15;
          int sw = (p & 7) ^ ((p >> 3) & 7);
          int gs = (gq & 0x18) | ((gq ^ sw) & 7);
          af[i] = *(const f16x8*)&Xl[(p << 8) + (gs << 3)];
        }
#pragma unroll
        for (int j = 0; j < 4; ++j) {
          int o = ot * 128 + wo + j * 16 + l15;
          bfr[j] = *(const f16x8*)(Wf + (size_t)o * 256 + kc * 64 + ks * 32 + q4 * 8);
        }
#pragma unroll
        for (int i = 0; i < 4; ++i)
#pragma unroll
          for (int j = 0; j < 4; ++j)
            acc[i][j] = MFMA_F16(af[i], bfr[j], acc[i][j]);
      }
    }

#pragma unroll
    for (int i = 0; i < 4; ++i) {
#pragma unroll
      for (int j = 0; j < 4; ++j) {
        int o = ot * 128 + wo + j * 16 + l15;
        int nn = o >> 6, d = o & 63;
#pragma unroll
        for (int r = 0; r < 4; ++r) {
          int p = p0 + wp + i * 16 + q4 * 4 + r;
          OUT[(((size_t)b * 8 + nn) * 16384 + p) * 64 + d] = (f16_t)acc[i][j][r];
        }
      }
    }
  }
}

// ---------------------------------------------------------------------------
// Stage B: 7x7 local attention, online softmax, dy-paired (each thread owns
// 2 vertically adjacent pixels -> each LDS K/V chunk read serves 2 px-dy).
// Block = 4 pixel rows x 64 w; threads = (rp 2, w 64, dg 2) = 256.
// 2-slot LDS ring of K|V rows (70 px x 16 chunks x 16B, XOR swizzle); 12 its.
// Zero halo == reference zero padding (OOB logits 0 participate in softmax).
// grid: [4 b][8 n][32 rowquad][2 whalf] = 2048 blocks x 256 thr
// ---------------------------------------------------------------------------
__global__ __launch_bounds__(256, 4) void attn_kernel(
    const f16_t* __restrict__ qh, const f16_t* __restrict__ kh,
    const f16_t* __restrict__ vh, f16_t* __restrict__ ao)
{
  int bid = blockIdx.x;
  const int wh = bid & 1;  bid >>= 1;
  const int hq = bid & 31; bid >>= 5;
  const int n  = bid & 7;  bid >>= 3;
  const int b  = bid;
  const int h0 = hq * 4, w0 = wh * 64;

  const int tid = threadIdx.x;
  const int rp = tid >> 7;          // row-pair (wave-uniform)
  const int w  = (tid >> 1) & 63;
  const int dg = tid & 1;           // 32-channel group
  const int dg4 = dg * 4;
  const int hA = h0 + 2 * rp, hB = hA + 1;

  const size_t headoff = ((size_t)b * 8 + n) * 16384 * 64;
  const f16_t* Qh = qh + headoff;
  const f16_t* Kh = kh + headoff;
  const f16_t* Vh = vh + headoff;

  __shared__ uint4 ring[2][70 * 16];  // [slot][pix*16 + (oc ^ (pix&15))]

  union Pack { uint4 u[4]; h2 h[16]; };

  Pack quA, quB;
  {
    const uint4* qa = (const uint4*)(Qh + ((size_t)hA * 128 + w0 + w) * 64 + dg * 32);
    const uint4* qb = (const uint4*)(Qh + ((size_t)hB * 128 + w0 + w) * 64 + dg * 32);
#pragma unroll
    for (int j = 0; j < 4; ++j) { quA.u[j] = qa[j]; quB.u[j] = qb[j]; }
  }

  auto load_row = [&](int r, int slot) {
#pragma unroll
    for (int t = 0; t < 5; ++t) {
      int task = t * 256 + tid;            // 70*16 = 1120 16B-chunk tasks
      if (task < 1120) {
        int pix = task >> 4, oc = task & 15;
        int ww = w0 + pix - 3;
        uint4 val = make_uint4(0u, 0u, 0u, 0u);
        if (r >= 0 && r < 128 && ww >= 0 && ww < 128) {
          const f16_t* src = (oc < 8)
              ? (Kh + ((size_t)r * 128 + ww) * 64 + oc * 8)
              : (Vh + ((size_t)r * 128 + ww) * 64 + (oc - 8) * 8);
          val = *(const uint4*)src;
        }
        ring[slot][(pix << 4) + (oc ^ (pix & 15))] = val;
      }
    }
  };

  const float cscale = 0.18033688011112042f;  // (1/8) * log2(e)

  float mA = -3.0e38f, lA = 0.f, mB = -3.0e38f, lB = 0.f;
  h2 ovA[16], ovB[16];
#pragma unroll
  for (int j = 0; j < 16; ++j) { ovA[j] = (h2){(f16_t)0.f, (f16_t)0.f}; ovB[j] = ovA[j]; }

  load_row(h0 - 3, 0);
  __syncthreads();

#pragma unroll 1
  for (int it = 0; it < 12; ++it) {
    if (it < 11) load_row(h0 - 2 + it, (it + 1) & 1);  // prefetch next row
    const uint4* cur = ring[it & 1];
    const int dyA = it - 2 * rp;                        // wave-uniform
    const int dyB = dyA - 1;
    const bool aA = (dyA >= 0) && (dyA < 7);
    const bool aB = (dyB >= 0) && (dyB < 7);
    if (aA || aB) {
      // ---- scores vs this k-row for both owned pixels ----
      float sA[7], sB[7];
#pragma unroll
      for (int dx = 0; dx < 7; ++dx) {
        const int pix = w + dx, sw = pix & 15, base = pix << 4;
        Pack ku;
        ku.u[0] = cur[base + ((dg4 + 0) ^ sw)];
        ku.u[1] = cur[base + ((dg4 + 1) ^ sw)];
        ku.u[2] = cur[base + ((dg4 + 2) ^ sw)];
        ku.u[3] = cur[base + ((dg4 + 3) ^ sw)];
        float accA = 0.f, accB = 0.f;
#pragma unroll
        for (int j = 0; j < 16; ++j) {
          accA = fdot2_(quA.h[j], ku.h[j], accA);
          accB = fdot2_(quB.h[j], ku.h[j], accB);
        }
        sA[dx] = accA; sB[dx] = accB;
      }
#pragma unroll
      for (int dx = 0; dx < 7; ++dx) {
        sA[dx] = (sA[dx] + __shfl_xor(sA[dx], 1)) * cscale;
        sB[dx] = (sB[dx] + __shfl_xor(sB[dx], 1)) * cscale;
      }

      // ---- online softmax updates ----
      h2 eA[7], eB[7];
      if (aA) {
        float nm = mA;
#pragma unroll
        for (int dx = 0; dx < 7; ++dx) nm = fmaxf(nm, sA[dx]);
        float alpha = exp2f(mA - nm);
        mA = nm; lA *= alpha;
        f16_t ah = (f16_t)alpha; h2 a2 = (h2){ah, ah};
#pragma unroll
        for (int j = 0; j < 16; ++j) ovA[j] *= a2;
#pragma unroll
        for (int dx = 0; dx < 7; ++dx) {
          float e = exp2f(sA[dx] - mA);
          lA += e; f16_t eh = (f16_t)e; eA[dx] = (h2){eh, eh};
        }
      }
      if (aB) {
        float nm = mB;
#pragma unroll
        for (int dx = 0; dx < 7; ++dx) nm = fmaxf(nm, sB[dx]);
        float alpha = exp2f(mB - nm);
        mB = nm; lB *= alpha;
        f16_t ah = (f16_t)alpha; h2 a2 = (h2){ah, ah};
#pragma unroll
        for (int j = 0; j < 16; ++j) ovB[j] *= a2;
#pragma unroll
        for (int dx = 0; dx < 7; ++dx) {
          float e = exp2f(sB[dx] - mB);
          lB += e; f16_t eh = (f16_t)e; eB[dx] = (h2){eh, eh};
        }
      }

      // ---- weighted V (chunk read shared by both pixels) ----
#pragma unroll
      for (int dx = 0; dx < 7; ++dx) {
        const int pix = w + dx, sw = pix & 15, base = pix << 4;
        Pack vu;
        vu.u[0] = cur[base + ((8 + dg4 + 0) ^ sw)];
        vu.u[1] = cur[base + ((8 + dg4 + 1) ^ sw)];
        vu.u[2] = cur[base + ((8 + dg4 + 2) ^ sw)];
        vu.u[3] = cur[base + ((8 + dg4 + 3) ^ sw)];
        if (aA) {
#pragma unroll
          for (int j = 0; j < 16; ++j) ovA[j] = eA[dx] * vu.h[j] + ovA[j];
        }
        if (aB) {
#pragma unroll
          for (int j = 0; j < 16; ++j) ovB[j] = eB[dx] * vu.h[j] + ovB[j];
        }
      }
    }
    __syncthreads();
  }

  // epilogue: normalize, store 32 f16 channels per owned pixel
  {
    float inv = 1.0f / lA; f16_t ih = (f16_t)inv; h2 i2 = (h2){ih, ih};
    Pack ou;
#pragma unroll
    for (int j = 0; j < 16; ++j) ou.h[j] = ovA[j] * i2;
    uint4* d4 = (uint4*)(ao + (((size_t)b * 16384) + (size_t)hA * 128 + (w0 + w)) * 512 + n * 64 + dg * 32);
    d4[0] = ou.u[0]; d4[1] = ou.u[1]; d4[2] = ou.u[2]; d4[3] = ou.u[3];
  }
  {
    float inv = 1.0f / lB; f16_t ih = (f16_t)inv; h2 i2 = (h2){ih, ih};
    Pack ou;
#pragma unroll
    for (int j = 0; j < 16; ++j) ou.h[j] = ovB[j] * i2;
    uint4* d4 = (uint4*)(ao + (((size_t)b * 16384) + (size_t)hB * 128 + (w0 + w)) * 512 + n * 64 + dg * 32);
    d4[0] = ou.u[0]; d4[1] = ou.u[1]; d4[2] = ou.u[2]; d4[3] = ou.u[3];
  }
}

// ---------------------------------------------------------------------------
// Stage C: o = Wfc @ ao + residual, LayerNorm over C=256, fused.
// ao tile staged ONCE ([p=64][k=512] f16, 64 KB); A-fragments of Wfc_f16
// gathered directly from L2-hot global.  2 barriers/block.
// grid: [4 b][256 ptile(64)] = 1024 blocks x 256 thr
// ---------------------------------------------------------------------------
__global__ __launch_bounds__(256, 2) void fc_ln_kernel(
    const f16_t* __restrict__ ao, const f16_t* __restrict__ Wfc16,
    const float* __restrict__ resid, const float* __restrict__ lnw,
    const float* __restrict__ lnb, float* __restrict__ outp)
{
  int bid = blockIdx.x;
  const int pt = bid & 255;
  const int b = bid >> 8;
  const int p0 = pt * 64;

  const int tid = threadIdx.x;
  const int lane = tid & 63, wv = tid >> 6;
  const int c0w = wv * 64;
  const int l15 = lane & 15, q4 = lane >> 4;

  __shared__ __align__(16) f16_t Bl[64 * 512];  // ao tile [p][k], 64 KB
  __shared__ float lnws[256], lnbs[256];
  __shared__ float red[2][4][64];

  lnws[tid] = lnw[tid];
  lnbs[tid] = lnb[tid];

  // stage full ao tile once
#pragma unroll
  for (int t = 0; t < 16; ++t) {
    int task = t * 256 + tid;            // 4096 tasks: (p 64) x (g 64)
    int p = task >> 6, g = task & 63;
    uint4 v4 = *(const uint4*)(ao + ((size_t)b * 16384 + p0 + p) * 512 + g * 8);
    int gs = (g & 0x38) | ((g ^ (p & 7)) & 7);
    *(uint4*)&Bl[(p << 9) + (gs << 3)] = v4;
  }
  __syncthreads();

  f32x4 acc[4][4];
#pragma unroll
  for (int i = 0; i < 4; ++i)
#pragma unroll
    for (int j = 0; j < 4; ++j) acc[i][j] = (f32x4){0.f, 0.f, 0.f, 0.f};

#pragma unroll 1
  for (int kc = 0; kc < 8; ++kc) {
#pragma unroll
    for (int ks = 0; ks < 2; ++ks) {
      const int gq = kc * 8 + ks * 4 + q4;     // chunk 0..63
      f16x8 af[4], bfr[4];
#pragma unroll
      for (int i = 0; i < 4; ++i) {
        int c = c0w + i * 16 + l15;
        af[i] = *(const f16x8*)(Wfc16 + (size_t)c * 512 + kc * 64 + ks * 32 + q4 * 8);
      }
#pragma unroll
      for (int j = 0; j < 4; ++j) {
        int p = j * 16 + l15;
        int gs = (gq & 0x38) | ((gq ^ (p & 7)) & 7);
        bfr[j] = *(const f16x8*)&Bl[(p << 9) + (gs << 3)];
      }
#pragma unroll
      for (int i = 0; i < 4; ++i)
#pragma unroll
        for (int j = 0; j < 4; ++j)
          acc[i][j] = MFMA_F16(af[i], bfr[j], acc[i][j]);
    }
  }

  float s[4], s2[4];
#pragma unroll
  for (int j = 0; j < 4; ++j) { s[j] = 0.f; s2[j] = 0.f; }
#pragma unroll
  for (int i = 0; i < 4; ++i) {
#pragma unroll
    for (int r = 0; r < 4; ++r) {
      int c = c0w + i * 16 + q4 * 4 + r;
      const float* rp = resid + ((size_t)b * 256 + c) * 16384 + p0;
#pragma unroll
      for (int j = 0; j < 4; ++j) {
        float v = acc[i][j][r] + rp[j * 16 + l15];
        acc[i][j][r] = v;
        s[j] += v; s2[j] += v * v;
      }
    }
  }
#pragma unroll
  for (int j = 0; j < 4; ++j) {
    s[j]  += __shfl_xor(s[j], 16);
    s[j]  += __shfl_xor(s[j], 32);
    s2[j] += __shfl_xor(s2[j], 16);
    s2[j] += __shfl_xor(s2[j], 32);
  }
  if (q4 == 0) {
#pragma unroll
    for (int j = 0; j < 4; ++j) {
      red[0][wv][j * 16 + l15] = s[j];
      red[1][wv][j * 16 + l15] = s2[j];
    }
  }
  __syncthreads();
#pragma unroll
  for (int j = 0; j < 4; ++j) {
    int pl = j * 16 + l15;
    float ts  = red[0][0][pl] + red[0][1][pl] + red[0][2][pl] + red[0][3][pl];
    float ts2 = red[1][0][pl] + red[1][1][pl] + red[1][2][pl] + red[1][3][pl];
    float mean = ts * (1.f / 256.f);
    float var  = ts2 * (1.f / 256.f) - mean * mean;
    float rstd = rsqrtf(var + 1e-6f);
#pragma unroll
    for (int i = 0; i < 4; ++i) {
#pragma unroll
      for (int r = 0; r < 4; ++r) {
        int c = c0w + i * 16 + q4 * 4 + r;
        outp[((size_t)b * 256 + c) * 16384 + p0 + pl] =
            (acc[i][j][r] - mean) * rstd * lnws[c] + lnbs[c];
      }
    }
  }
}

// ---------------------------------------------------------------------------
extern "C" void kernel_launch(void* const* d_in, const int* in_sizes, int n_in,
                              void* d_out, int out_size, void* d_ws, size_t ws_size,
                              hipStream_t stream) {
  const float* q   = (const float*)d_in[0];
  const float* k   = (const float*)d_in[1];
  const float* v   = (const float*)d_in[2];
  const float* Wq  = (const float*)d_in[3];
  const float* Wk  = (const float*)d_in[4];
  const float* Wv  = (const float*)d_in[5];
  const float* Wfc = (const float*)d_in[6];
  const float* lnw = (const float*)d_in[7];
  const float* lnb = (const float*)d_in[8];
  float* outp = (float*)d_out;

  // workspace: 4 x 64 MiB f16 regions; W_f16 copies overlay dead regions:
  //   Wqkv_f16 -> head of ao region (dead until attn rewrites it fully)
  //   Wfc_f16  -> head of qh region (dead after attn)
  f16_t* qh = (f16_t*)d_ws;
  f16_t* kh = qh + 33554432ULL;
  f16_t* vh = kh + 33554432ULL;
  f16_t* ao = vh + 33554432ULL;
  f16_t* Wqkv16 = ao;   // 393216 f16, consumed by proj before attn writes ao
  f16_t* Wfc16  = qh;   // 131072 f16, written after attn, consumed by fc_ln

  wconvA_kernel<<<dim3(384), dim3(256), 0, stream>>>(Wq, Wk, Wv, Wqkv16);
  proj_kernel<<<dim3(1536), dim3(256), 0, stream>>>(q, k, v, Wqkv16, qh, kh, vh);
  attn_kernel<<<dim3(2048), dim3(256), 0, stream>>>(qh, kh, vh, ao);
  wconvB_kernel<<<dim3(128), dim3(256), 0, stream>>>(Wfc, Wfc16);
  fc_ln_kernel<<<dim3(1024), dim3(256), 0, stream>>>(ao, Wfc16, q, lnw, lnb, outp);
}